// Round 1
// baseline (179.331 us; speedup 1.0000x reference)
//
#include <hip/hip_runtime.h>

// MultiHeadSelfAttention: B=2, S=2048, E=768, H=12, D=64
// R12: GEMMs reverted to all-wave glds16 DMA (R10) but restructured to
//      prefetch-before-compute: DMA for tile s+1 issued into the other LDS
//      slot BEFORE consuming tile s, one barrier/iter -> drain overlapped by
//      the ds_read+MFMA phase. Flash/prep = R10 (57.9us verified).
// R13: identical resubmit — previous bench failed on infra (container), no
//      counters; re-running unchanged to anchor the baseline.

typedef __bf16 bf16_t;
typedef bf16_t bf16x8 __attribute__((ext_vector_type(8)));
typedef bf16_t bf16x4 __attribute__((ext_vector_type(4)));
typedef float f32x4 __attribute__((ext_vector_type(4)));
typedef _Float16 f16x4 __attribute__((ext_vector_type(4)));
typedef __fp16 hf2 __attribute__((ext_vector_type(2)));

#define SC2 0.1803368801111137f  // 0.125 * log2(e): qk-scale folded into exp2

__device__ __forceinline__ float bf2f(unsigned short u) {
  union { unsigned int i; float f; } x;
  x.i = ((unsigned int)u) << 16;
  return x.f;
}

__device__ __forceinline__ float fexp2(float x) {
  return __builtin_amdgcn_exp2f(x);  // raw v_exp_f32; args <= 0 here, FTZ exact
}

__device__ __forceinline__ void glds16(const bf16_t* g, bf16_t* l) {
  __builtin_amdgcn_global_load_lds(
      (const __attribute__((address_space(1))) void*)g,
      (__attribute__((address_space(3))) void*)l, 16, 0, 0);
}

// dtype probe: wave examines first 1024 u16 words of x. fp32 data => low
// halves carry random mantissa bits => wild bf16 exponents.
__device__ __forceinline__ int detect_bf16_flag(const unsigned short* x) {
  const int lane = threadIdx.x & 63;
  const uint4* p = (const uint4*)x;
  uint4 a = p[lane * 2];
  uint4 b = p[lane * 2 + 1];
  unsigned int w[8] = {a.x, a.y, a.z, a.w, b.x, b.y, b.z, b.w};
  unsigned int big = 0;
#pragma unroll
  for (int i = 0; i < 8; i++) {
    unsigned int e0 = (w[i] >> 7) & 0xFF, e1 = (w[i] >> 23) & 0xFF;
    big |= (e0 > 0x88u) | (e1 > 0x88u);
  }
  unsigned long long bal = __ballot(big != 0u);
  return bal == 0ULL ? 1 : 0;  // 1 => bf16 inputs
}

// ---------------------------------------------------------------- fused prep
__global__ void k_prep(const void* __restrict__ x, const void* __restrict__ mask,
                       const void* __restrict__ Wq, const void* __restrict__ Wk,
                       const void* __restrict__ Wv, const void* __restrict__ Wo,
                       bf16_t* __restrict__ xb, bf16_t* __restrict__ wqkvT,
                       bf16_t* __restrict__ woT, int* __restrict__ mflags) {
  __shared__ float ts[32][33];
  __shared__ int snz;
  const int blk = blockIdx.x;
  const int f = detect_bf16_flag((const unsigned short*)x);

  if (blk < 1536) {  // ---- ingest x (fp32 only; bf16 path reads x directly)
    if (f) return;
    int i = blk * 256 + threadIdx.x;
    const float* xf = (const float*)x + (size_t)i * 8;
    bf16x8 v;
#pragma unroll
    for (int j = 0; j < 8; j++) v[j] = (bf16_t)xf[j];
    *(bf16x8*)(xb + (size_t)i * 8) = v;
  } else if (blk < 3840) {  // ---- W transpose (4 matrices x 24x24 tiles)
    const int t = blk - 1536;
    const int z = t / 576, r = t % 576, kt = r / 24, nt = r % 24;
    const void* wsrc = (z == 0) ? Wq : (z == 1) ? Wk : (z == 2) ? Wv : Wo;
    bf16_t* dst = (z < 3) ? (wqkvT + (size_t)z * 768 * 768) : woT;
    const int c = threadIdx.x & 31, r0 = threadIdx.x >> 5;
#pragma unroll
    for (int i = 0; i < 4; i++) {
      int kr = kt * 32 + r0 + i * 8;
      float v;
      if (f) v = bf2f(((const unsigned short*)wsrc)[(size_t)kr * 768 + nt * 32 + c]);
      else   v = ((const float*)wsrc)[(size_t)kr * 768 + nt * 32 + c];
      ts[r0 + i * 8][c] = v;
    }
    __syncthreads();
#pragma unroll
    for (int i = 0; i < 4; i++) {
      int nr = nt * 32 + r0 + i * 8;
      dst[(size_t)nr * 768 + kt * 32 + c] = (bf16_t)ts[c][r0 + i * 8];
    }
  } else {  // ---- mask nonzero flag per 128x128 tile, uint4 loads
    const int t = blk - 3840;
    const int qt = t >> 4, ktm = t & 15;
    if (threadIdx.x == 0) snz = 0;
    __syncthreads();
    unsigned int nz = 0;
    if (f) {
#pragma unroll
      for (int i = 0; i < 8; i++) {
        int uidx = i * 256 + threadIdx.x;
        int row = uidx >> 4, col = uidx & 15;
        const uint4* p = (const uint4*)((const char*)mask +
            ((size_t)(qt * 128 + row) * 2048 + ktm * 128) * 2 + col * 16);
        uint4 v = *p;
        nz |= ((v.x | v.y | v.z | v.w) & 0x7fff7fffu);
      }
    } else {
#pragma unroll
      for (int i = 0; i < 16; i++) {
        int uidx = i * 256 + threadIdx.x;
        int row = uidx >> 5, col = uidx & 31;
        const uint4* p = (const uint4*)((const char*)mask +
            ((size_t)(qt * 128 + row) * 2048 + ktm * 128) * 4 + col * 16);
        uint4 v = *p;
        nz |= ((v.x | v.y | v.z | v.w) & 0x7fffffffu);
      }
    }
    if (nz) snz = 1;
    __syncthreads();
    if (threadIdx.x == 0) mflags[qt * 16 + ktm] = snz;
  }
}

// ------------------------------------------------------------------ QKV GEMM
// C[4096 x 2304] = A * wqkvT^T, 128x128 tile, BK=32 double-buffered with
// prefetch-before-compute: DMA s+1 -> other slot, then consume slot s,
// then one barrier (drain overlapped by compute).
__global__ __launch_bounds__(256, 3) void k_gemmQKV(
    const bf16_t* __restrict__ xb, const bf16_t* __restrict__ Bm,
    bf16_t* __restrict__ Qd, bf16_t* __restrict__ Kd, _Float16* __restrict__ Vt,
    const unsigned short* __restrict__ xdet) {
  __shared__ __align__(16) char smem[32768];  // A slots @0,8192 | B @16384,24576
  _Float16* Tb = (_Float16*)smem;             // V epilogue reuse (17.4KB)

  const int f = detect_bf16_flag(xdet);
  const bf16_t* A = f ? (const bf16_t*)xdet : xb;

  const int tid = threadIdx.x;
  const int n0 = blockIdx.x * 128, m0 = blockIdx.y * 128;
  const int r = tid >> 2, c8 = (tid & 3) << 3;
  const bf16_t* Ag = A + (size_t)(m0 + r) * 768 + c8;
  const bf16_t* Bg = Bm + (size_t)(n0 + r) * 768 + c8;
  const int wid = tid >> 6, lane = tid & 63;
  const int wm = (wid >> 1) << 6, wn = (wid & 1) << 6;
  const int lr = lane & 15, lk = (lane >> 4) << 3, g4 = (lane >> 4) << 2;

  f32x4 acc[4][4];
  const f32x4 z = {0.f, 0.f, 0.f, 0.f};
#pragma unroll
  for (int i = 0; i < 4; i++)
#pragma unroll
    for (int j = 0; j < 4; j++) acc[i][j] = z;

  {  // stage k0=0 -> slot 0
    bf16_t* A0 = (bf16_t*)smem;
    bf16_t* B0 = (bf16_t*)(smem + 16384);
    glds16(Ag, A0 + wid * 512);
    glds16(Ag + (size_t)64 * 768, A0 + 2048 + wid * 512);
    glds16(Bg, B0 + wid * 512);
    glds16(Bg + (size_t)64 * 768, B0 + 2048 + wid * 512);
  }
  __syncthreads();

  for (int s = 0; s < 24; s++) {
    if (s < 23) {  // prefetch s+1 into other slot (overlaps compute below)
      const int k0 = (s + 1) * 32;
      bf16_t* An = (bf16_t*)(smem + ((s + 1) & 1) * 8192);
      bf16_t* Bn = (bf16_t*)(smem + 16384 + ((s + 1) & 1) * 8192);
      glds16(Ag + k0, An + wid * 512);
      glds16(Ag + (size_t)64 * 768 + k0, An + 2048 + wid * 512);
      glds16(Bg + k0, Bn + wid * 512);
      glds16(Bg + (size_t)64 * 768 + k0, Bn + 2048 + wid * 512);
    }
    const bf16_t* As = (const bf16_t*)(smem + (s & 1) * 8192);
    const bf16_t* Bs = (const bf16_t*)(smem + 16384 + (s & 1) * 8192);
    bf16x8 af[4], bf_[4];
#pragma unroll
    for (int t = 0; t < 4; t++) af[t]  = *(const bf16x8*)&As[(wm + t * 16 + lr) * 32 + lk];
#pragma unroll
    for (int t = 0; t < 4; t++) bf_[t] = *(const bf16x8*)&Bs[(wn + t * 16 + lr) * 32 + lk];
#pragma unroll
    for (int i = 0; i < 4; i++)
#pragma unroll
      for (int j = 0; j < 4; j++)
        acc[i][j] = __builtin_amdgcn_mfma_f32_16x16x32_bf16(af[i], bf_[j], acc[i][j], 0, 0, 0);
    __syncthreads();  // joins waves + drains this iter's DMA (issued pre-compute)
  }

  if (n0 < 1536) {  // Q or K: scatter (16-lane runs contiguous over d)
    bf16_t* dst = (n0 < 768) ? Qd : Kd;
    const int nb = (n0 < 768) ? n0 : n0 - 768;
    const int bb = m0 >> 11;
#pragma unroll
    for (int i = 0; i < 4; i++)
#pragma unroll
      for (int j = 0; j < 4; j++) {
        const int rc = nb + wn + j * 16 + lr;
        const int hh = rc >> 6, dd = rc & 63;
        const size_t base = (((size_t)bb * 12 + hh) * 2048) * 64 + dd;
#pragma unroll
        for (int reg = 0; reg < 4; reg++) {
          const int s = (m0 & 2047) + wm + i * 16 + g4 + reg;
          dst[base + (size_t)s * 64] = (bf16_t)acc[i][j][reg];
        }
      }
  } else {  // V: LDS transpose -> coalesced V^T f16 writes
    const int bb = m0 >> 11;
#pragma unroll
    for (int half = 0; half < 2; half++) {
      if ((wid & 1) == half) {
#pragma unroll
        for (int j = 0; j < 4; j++) {
          const int d_l = j * 16 + lr;
#pragma unroll
          for (int i = 0; i < 4; i++)
#pragma unroll
            for (int reg = 0; reg < 4; reg++)
              Tb[d_l * 136 + wm + i * 16 + g4 + reg] = (_Float16)acc[i][j][reg];
        }
      }
      __syncthreads();
      const int row = tid >> 2, cc = (tid & 3) * 32;
      const int vcol = (n0 - 1536) + half * 64 + row;
      const int hh = vcol >> 6;  // d == row
      _Float16* dstv = Vt + (((size_t)bb * 12 + hh) * 64 + row) * 2048 + (m0 & 2047) + cc;
#pragma unroll
      for (int u = 0; u < 4; u++)
        *(uint4*)(dstv + u * 8) = *(const uint4*)&Tb[row * 136 + cc + u * 8];
      __syncthreads();
    }
  }
}

// ----------------------------------------------------------- flash attention
// R10 structure (verified 57.9us): 768 blocks x 320 thr, 4 consumers +
// producer, double-buffer, ones-MFMA row-sum.
__global__ __launch_bounds__(320, 4) void k_flash(
    const bf16_t* __restrict__ Qd, const bf16_t* __restrict__ Kd,
    const _Float16* __restrict__ Vt, const void* __restrict__ mask,
    const int* __restrict__ mflags, const unsigned short* __restrict__ xdet,
    bf16_t* __restrict__ attn) {
  __shared__ __align__(16) char sm[32768];  // buf p at p*16384: K 8KB | V 8KB

  const int tid = threadIdx.x, wid = tid >> 6, lane = tid & 63;
  const int lr = lane & 15, quad = lane >> 4, lk = quad << 3, g4 = quad << 2;

  const int lin = blockIdx.x;
  const int gx = lin & 7, ww = lin >> 3;
  const int hb = gx * 3 + (ww >> 5);
  const int h = hb % 12, bb = hb / 12;
  const int qt = ww & 31;

  const size_t bh = (size_t)bb * 12 + h;
  const char* Kh = (const char*)(Kd + bh * 2048 * 64);
  const char* Vh = (const char*)(Vt + bh * 64 * 2048);

  if (wid == 4) {
    const char* kS[8]; const char* vS[8];
#pragma unroll
    for (int u = 0; u < 8; u++) {
      const int R = (u >> 1) * 16 + lr;
      const int c = (u & 1) * 4 + quad;
      kS[u] = Kh + R * 128 + c * 16;
      const int u2 = u * 2 + (lane >> 5);
      const int dtv = u2 & 3, ctv = u2 >> 2, j2 = lane & 31;
      vS[u] = Vh + (size_t)(dtv * 16 + (j2 & 15)) * 4096 + ctv * 32 + (j2 >> 4) * 16;
    }
    uint4 kv[8], vv[8];
#pragma unroll
    for (int u = 0; u < 8; u++) kv[u] = *(const uint4*)(kS[u]);
#pragma unroll
    for (int u = 0; u < 8; u++) vv[u] = *(const uint4*)(vS[u]);
#pragma unroll
    for (int u = 0; u < 8; u++) *(uint4*)(sm + u * 1024 + lane * 16) = kv[u];
#pragma unroll
    for (int u = 0; u < 8; u++) *(uint4*)(sm + 8192 + u * 1024 + lane * 16) = vv[u];
    __syncthreads();
    for (int s = 0; s < 32; s++) {
      if (s < 31) {
        const int t = s + 1;
        char* buf = sm + (t & 1) * 16384;
#pragma unroll
        for (int u = 0; u < 8; u++) kv[u] = *(const uint4*)(kS[u] + (size_t)t * 8192);
#pragma unroll
        for (int u = 0; u < 8; u++) vv[u] = *(const uint4*)(vS[u] + (size_t)t * 128);
#pragma unroll
        for (int u = 0; u < 8; u++) *(uint4*)(buf + u * 1024 + lane * 16) = kv[u];
#pragma unroll
        for (int u = 0; u < 8; u++) *(uint4*)(buf + 8192 + u * 1024 + lane * 16) = vv[u];
      }
      __syncthreads();
    }
    return;
  }

  const bf16_t* Qh = Qd + bh * 2048 * 64;
  const int q0 = qt * 64 + wid * 16;
  const int mbf = detect_bf16_flag(xdet);
  const int* mfrow = mflags + (qt >> 1) * 16;
  int mbits = 0;
#pragma unroll
  for (int t = 0; t < 16; t++) mbits |= (mfrow[t] != 0) << t;

  const bf16x8 qf0 = *(const bf16x8*)&Qh[(size_t)(q0 + lr) * 64 + lk];
  const bf16x8 qf1 = *(const bf16x8*)&Qh[(size_t)(q0 + lr) * 64 + 32 + lk];

  f16x4 ones;
  ones[0] = (_Float16)1.f; ones[1] = (_Float16)1.f;
  ones[2] = (_Float16)1.f; ones[3] = (_Float16)1.f;

  const f32x4 z = {0.f, 0.f, 0.f, 0.f};
  f32x4 ot[4];
#pragma unroll
  for (int dt = 0; dt < 4; dt++) ot[dt] = z;
  float mrow = -1e30f, lrow = 0.f;

  __syncthreads();

  for (int s = 0; s < 32; s++) {
    const char* Kc = sm + (s & 1) * 16384;
    const char* Vc = Kc + 8192;

    f32x4 sv[4];
#pragma unroll
    for (int ct = 0; ct < 4; ct++) sv[ct] = z;
#pragma unroll
    for (int ct = 0; ct < 4; ct++) {
      bf16x8 kf0 = *(const bf16x8*)(Kc + ct * 2048 + lane * 16);
      bf16x8 kf1 = *(const bf16x8*)(Kc + ct * 2048 + 1024 + lane * 16);
      sv[ct] = __builtin_amdgcn_mfma_f32_16x16x32_bf16(kf0, qf0, sv[ct], 0, 0, 0);
      sv[ct] = __builtin_amdgcn_mfma_f32_16x16x32_bf16(kf1, qf1, sv[ct], 0, 0, 0);
    }

    if ((mbits >> (s >> 1)) & 1) {
#pragma unroll
      for (int ct = 0; ct < 4; ct++)
#pragma unroll
        for (int reg = 0; reg < 4; reg++) {
          size_t mi = (size_t)(q0 + lr) * 2048 + s * 64 + ct * 16 + g4 + reg;
          float mv = mbf ? bf2f(((const unsigned short*)mask)[mi])
                         : ((const float*)mask)[mi];
          sv[ct][reg] -= 8e9f * mv;
        }
    }

    float t = fmaxf(
        fmaxf(fmaxf(fmaxf(sv[0][0], sv[0][1]), fmaxf(sv[0][2], sv[0][3])),
              fmaxf(fmaxf(sv[1][0], sv[1][1]), fmaxf(sv[1][2], sv[1][3]))),
        fmaxf(fmaxf(fmaxf(sv[2][0], sv[2][1]), fmaxf(sv[2][2], sv[2][3])),
              fmaxf(fmaxf(sv[3][0], sv[3][1]), fmaxf(sv[3][2], sv[3][3]))));
    t = fmaxf(t, __shfl_xor(t, 16));
    t = fmaxf(t, __shfl_xor(t, 32));
    const float mnew = fmaxf(mrow, t);
    if (__ballot(mnew > mrow)) {
      const float alpha = fexp2((mrow - mnew) * SC2);
#pragma unroll
      for (int dt = 0; dt < 4; dt++)
#pragma unroll
        for (int reg = 0; reg < 4; reg++) ot[dt][reg] *= alpha;
      lrow *= alpha;
    }
    mrow = mnew;
    const float mS = mnew * SC2;

    f16x4 pb[4];
#pragma unroll
    for (int ct = 0; ct < 4; ct++) {
      float p0 = fexp2(fmaf(sv[ct][0], SC2, -mS));
      float p1 = fexp2(fmaf(sv[ct][1], SC2, -mS));
      float p2 = fexp2(fmaf(sv[ct][2], SC2, -mS));
      float p3 = fexp2(fmaf(sv[ct][3], SC2, -mS));
      union { hf2 h[2]; f16x4 v; } u;
      u.h[0] = __builtin_amdgcn_cvt_pkrtz(p0, p1);
      u.h[1] = __builtin_amdgcn_cvt_pkrtz(p2, p3);
      pb[ct] = u.v;
    }

    f32x4 asum = z;
#pragma unroll
    for (int ct = 0; ct < 4; ct++) {
      asum = __builtin_amdgcn_mfma_f32_16x16x16f16(ones, pb[ct], asum, 0, 0, 0);
#pragma unroll
      for (int dt = 0; dt < 4; dt++) {
        f16x4 va = *(const f16x4*)(Vc + (ct * 4 + dt) * 512 +
                                   (quad >> 1) * 256 + lr * 16 + (quad & 1) * 8);
        ot[dt] = __builtin_amdgcn_mfma_f32_16x16x16f16(va, pb[ct], ot[dt], 0, 0, 0);
      }
    }
    lrow += asum[0];
    __syncthreads();
  }

  const float inv = 1.0f / lrow;
  bf16_t* arow = attn + ((size_t)bb * 2048 + q0 + lr) * 768 + h * 64 + g4;
#pragma unroll
  for (int dt = 0; dt < 4; dt++) {
    bf16x4 v;
#pragma unroll
    for (int reg = 0; reg < 4; reg++) v[reg] = (bf16_t)(ot[dt][reg] * inv);
    *(bf16x4*)(arow + dt * 16) = v;
  }
}

// -------------------------------------------------- output GEMM (attn @ Wo^T)
// 64x64 tiles -> 768 blocks (3/CU), BK=64 double-buffered with
// prefetch-before-compute (two 32-k sub-tiles per slot).
__global__ __launch_bounds__(256, 3) void k_gemm2(
    const bf16_t* __restrict__ A, const bf16_t* __restrict__ Bm,
    const void* __restrict__ bo, const unsigned short* __restrict__ xdet,
    float* __restrict__ outF, unsigned short* __restrict__ outH) {
  __shared__ __align__(16) char smem[32768];  // A slots @0,8192 | B @16384,24576

  const int tid = threadIdx.x, wid = tid >> 6, lane = tid & 63;
  const int n0 = blockIdx.x * 64, m0 = blockIdx.y * 64;
  const int wm = (wid >> 1) << 5, wn = (wid & 1) << 5;
  const int lr = lane & 15, lk = (lane >> 4) << 3, g4 = (lane >> 4) << 2;
  const bf16_t* Ag = A + (size_t)(m0 + (tid >> 2)) * 768 + ((tid & 3) << 3);
  const bf16_t* Bg = Bm + (size_t)(n0 + (tid >> 2)) * 768 + ((tid & 3) << 3);

  f32x4 acc[2][2];
  const f32x4 z = {0.f, 0.f, 0.f, 0.f};
#pragma unroll
  for (int i = 0; i < 2; i++)
#pragma unroll
    for (int j = 0; j < 2; j++) acc[i][j] = z;

  {  // stage k0=0 -> slot 0 (two 32-k halves per operand)
    bf16_t* A0 = (bf16_t*)smem;
    bf16_t* B0 = (bf16_t*)(smem + 16384);
    glds16(Ag, A0 + wid * 512);
    glds16(Ag + 32, A0 + 2048 + wid * 512);
    glds16(Bg, B0 + wid * 512);
    glds16(Bg + 32, B0 + 2048 + wid * 512);
  }
  __syncthreads();

  for (int s = 0; s < 12; s++) {
    if (s < 11) {  // prefetch s+1 into other slot
      const int k0 = (s + 1) * 64;
      bf16_t* An = (bf16_t*)(smem + ((s + 1) & 1) * 8192);
      bf16_t* Bn = (bf16_t*)(smem + 16384 + ((s + 1) & 1) * 8192);
      glds16(Ag + k0, An + wid * 512);
      glds16(Ag + k0 + 32, An + 2048 + wid * 512);
      glds16(Bg + k0, Bn + wid * 512);
      glds16(Bg + k0 + 32, Bn + 2048 + wid * 512);
    }
#pragma unroll
    for (int kc = 0; kc < 2; kc++) {
      const bf16_t* As = (const bf16_t*)(smem + (s & 1) * 8192) + kc * 2048;
      const bf16_t* Bs = (const bf16_t*)(smem + 16384 + (s & 1) * 8192) + kc * 2048;
      bf16x8 af[2], bf_[2];
#pragma unroll
      for (int i = 0; i < 2; i++) af[i]  = *(const bf16x8*)&As[(wm + i * 16 + lr) * 32 + lk];
#pragma unroll
      for (int j = 0; j < 2; j++) bf_[j] = *(const bf16x8*)&Bs[(wn + j * 16 + lr) * 32 + lk];
#pragma unroll
      for (int i = 0; i < 2; i++)
#pragma unroll
        for (int j = 0; j < 2; j++)
          acc[i][j] = __builtin_amdgcn_mfma_f32_16x16x32_bf16(af[i], bf_[j], acc[i][j], 0, 0, 0);
    }
    __syncthreads();
  }

  const int obf = detect_bf16_flag(xdet);
#pragma unroll
  for (int i = 0; i < 2; i++)
#pragma unroll
    for (int j = 0; j < 2; j++) {
      const int nn = n0 + wn + j * 16 + lr;
      const float bv = obf ? bf2f(((const unsigned short*)bo)[nn])
                           : ((const float*)bo)[nn];
#pragma unroll
      for (int reg = 0; reg < 4; reg++) {
        const int m = m0 + wm + i * 16 + g4 + reg;
        const float v = acc[i][j][reg] + bv;
        if (obf) outH[(size_t)m * 768 + nn] = __builtin_bit_cast(unsigned short, (bf16_t)v);
        else     outF[(size_t)m * 768 + nn] = v;
      }
    }
}

// -------------------------------------------------------------------- launch
extern "C" void kernel_launch(void* const* d_in, const int* in_sizes, int n_in,
                              void* d_out, int out_size, void* d_ws, size_t ws_size,
                              hipStream_t stream) {
  (void)in_sizes; (void)n_in; (void)out_size; (void)ws_size;
  const void* x    = d_in[0];
  const void* mask = d_in[1];
  const void* Wq   = d_in[2];
  const void* Wk   = d_in[3];
  const void* Wv   = d_in[4];
  const void* Wo   = d_in[5];
  const void* bo   = d_in[6];

  char* w = (char*)d_ws;
  size_t off = 0;
  auto take = [&](size_t b) -> void* {
    void* p = w + off;
    off = (off + b + 255) & ~(size_t)255;
    return p;
  };
  int*      mflags = (int*)take(256 * 4);
  bf16_t*   wqkvT  = (bf16_t*)take((size_t)2304 * 768 * 2);
  bf16_t*   woT    = (bf16_t*)take((size_t)768 * 768 * 2);
  bf16_t*   xb     = (bf16_t*)take((size_t)4096 * 768 * 2);
  bf16_t*   Qd     = (bf16_t*)take((size_t)3145728 * 2);
  bf16_t*   Kd     = (bf16_t*)take((size_t)3145728 * 2);
  _Float16* Vt     = (_Float16*)take((size_t)3145728 * 2);
  bf16_t*   attn   = xb;  // xb dead after QKV GEMM (flash output reuses it)

  k_prep<<<4096, 256, 0, stream>>>(x, mask, Wq, Wk, Wv, Wo, xb, wqkvT, woT, mflags);
  k_gemmQKV<<<dim3(18, 32), 256, 0, stream>>>(xb, wqkvT, Qd, Kd, Vt,
                                              (const unsigned short*)x);
  k_flash<<<768, 320, 0, stream>>>(Qd, Kd, Vt, mask, mflags,
                                   (const unsigned short*)x, attn);
  k_gemm2<<<dim3(12, 64), 256, 0, stream>>>(attn, woT, bo, (const unsigned short*)x,
                                            (float*)d_out, (unsigned short*)d_out);
}

// Round 2
// 178.055 us; speedup vs baseline: 1.0072x; 1.0072x over previous
//
#include <hip/hip_runtime.h>

// MultiHeadSelfAttention: B=2, S=2048, E=768, H=12, D=64
// R14: flash PV upgraded to full-rate mfma_f32_16x16x32_f16 via K-row
//      permutation in LDS (producer-side, precomputed addrs): QK output
//      slots are permuted so each lane's own 16 P-values pack directly into
//      two f16x8 B-fragments (zero shuffles). V restaged as [64d][64k]
//      XOR-swizzled tile -> conflict-free b128 A-fragments. + T5 setprio
//      around MFMA clusters, T13 defer-max (THR=44 ~ 8/SC2).
//      GEMMs/prep unchanged from R12 (attribution discipline).

typedef __bf16 bf16_t;
typedef bf16_t bf16x8 __attribute__((ext_vector_type(8)));
typedef bf16_t bf16x4 __attribute__((ext_vector_type(4)));
typedef float f32x4 __attribute__((ext_vector_type(4)));
typedef _Float16 f16x4 __attribute__((ext_vector_type(4)));
typedef _Float16 f16x8 __attribute__((ext_vector_type(8)));
typedef __fp16 hf2 __attribute__((ext_vector_type(2)));

#define SC2 0.1803368801111137f  // 0.125 * log2(e): qk-scale folded into exp2
#define DEFER_THR 44.0f          // ~8/SC2: defer-max rescale threshold (T13)

__device__ __forceinline__ float bf2f(unsigned short u) {
  union { unsigned int i; float f; } x;
  x.i = ((unsigned int)u) << 16;
  return x.f;
}

__device__ __forceinline__ float fexp2(float x) {
  return __builtin_amdgcn_exp2f(x);  // raw v_exp_f32; args <= 8 here, FTZ exact
}

__device__ __forceinline__ void glds16(const bf16_t* g, bf16_t* l) {
  __builtin_amdgcn_global_load_lds(
      (const __attribute__((address_space(1))) void*)g,
      (__attribute__((address_space(3))) void*)l, 16, 0, 0);
}

// dtype probe: wave examines first 1024 u16 words of x. fp32 data => low
// halves carry random mantissa bits => wild bf16 exponents.
__device__ __forceinline__ int detect_bf16_flag(const unsigned short* x) {
  const int lane = threadIdx.x & 63;
  const uint4* p = (const uint4*)x;
  uint4 a = p[lane * 2];
  uint4 b = p[lane * 2 + 1];
  unsigned int w[8] = {a.x, a.y, a.z, a.w, b.x, b.y, b.z, b.w};
  unsigned int big = 0;
#pragma unroll
  for (int i = 0; i < 8; i++) {
    unsigned int e0 = (w[i] >> 7) & 0xFF, e1 = (w[i] >> 23) & 0xFF;
    big |= (e0 > 0x88u) | (e1 > 0x88u);
  }
  unsigned long long bal = __ballot(big != 0u);
  return bal == 0ULL ? 1 : 0;  // 1 => bf16 inputs
}

// ---------------------------------------------------------------- fused prep
__global__ void k_prep(const void* __restrict__ x, const void* __restrict__ mask,
                       const void* __restrict__ Wq, const void* __restrict__ Wk,
                       const void* __restrict__ Wv, const void* __restrict__ Wo,
                       bf16_t* __restrict__ xb, bf16_t* __restrict__ wqkvT,
                       bf16_t* __restrict__ woT, int* __restrict__ mflags) {
  __shared__ float ts[32][33];
  __shared__ int snz;
  const int blk = blockIdx.x;
  const int f = detect_bf16_flag((const unsigned short*)x);

  if (blk < 1536) {  // ---- ingest x (fp32 only; bf16 path reads x directly)
    if (f) return;
    int i = blk * 256 + threadIdx.x;
    const float* xf = (const float*)x + (size_t)i * 8;
    bf16x8 v;
#pragma unroll
    for (int j = 0; j < 8; j++) v[j] = (bf16_t)xf[j];
    *(bf16x8*)(xb + (size_t)i * 8) = v;
  } else if (blk < 3840) {  // ---- W transpose (4 matrices x 24x24 tiles)
    const int t = blk - 1536;
    const int z = t / 576, r = t % 576, kt = r / 24, nt = r % 24;
    const void* wsrc = (z == 0) ? Wq : (z == 1) ? Wk : (z == 2) ? Wv : Wo;
    bf16_t* dst = (z < 3) ? (wqkvT + (size_t)z * 768 * 768) : woT;
    const int c = threadIdx.x & 31, r0 = threadIdx.x >> 5;
#pragma unroll
    for (int i = 0; i < 4; i++) {
      int kr = kt * 32 + r0 + i * 8;
      float v;
      if (f) v = bf2f(((const unsigned short*)wsrc)[(size_t)kr * 768 + nt * 32 + c]);
      else   v = ((const float*)wsrc)[(size_t)kr * 768 + nt * 32 + c];
      ts[r0 + i * 8][c] = v;
    }
    __syncthreads();
#pragma unroll
    for (int i = 0; i < 4; i++) {
      int nr = nt * 32 + r0 + i * 8;
      dst[(size_t)nr * 768 + kt * 32 + c] = (bf16_t)ts[c][r0 + i * 8];
    }
  } else {  // ---- mask nonzero flag per 128x128 tile, uint4 loads
    const int t = blk - 3840;
    const int qt = t >> 4, ktm = t & 15;
    if (threadIdx.x == 0) snz = 0;
    __syncthreads();
    unsigned int nz = 0;
    if (f) {
#pragma unroll
      for (int i = 0; i < 8; i++) {
        int uidx = i * 256 + threadIdx.x;
        int row = uidx >> 4, col = uidx & 15;
        const uint4* p = (const uint4*)((const char*)mask +
            ((size_t)(qt * 128 + row) * 2048 + ktm * 128) * 2 + col * 16);
        uint4 v = *p;
        nz |= ((v.x | v.y | v.z | v.w) & 0x7fff7fffu);
      }
    } else {
#pragma unroll
      for (int i = 0; i < 16; i++) {
        int uidx = i * 256 + threadIdx.x;
        int row = uidx >> 5, col = uidx & 31;
        const uint4* p = (const uint4*)((const char*)mask +
            ((size_t)(qt * 128 + row) * 2048 + ktm * 128) * 4 + col * 16);
        uint4 v = *p;
        nz |= ((v.x | v.y | v.z | v.w) & 0x7fffffffu);
      }
    }
    if (nz) snz = 1;
    __syncthreads();
    if (threadIdx.x == 0) mflags[qt * 16 + ktm] = snz;
  }
}

// ------------------------------------------------------------------ QKV GEMM
// C[4096 x 2304] = A * wqkvT^T, 128x128 tile, BK=32 double-buffered with
// prefetch-before-compute: DMA s+1 -> other slot, then consume slot s,
// then one barrier (drain overlapped by compute).
__global__ __launch_bounds__(256, 3) void k_gemmQKV(
    const bf16_t* __restrict__ xb, const bf16_t* __restrict__ Bm,
    bf16_t* __restrict__ Qd, bf16_t* __restrict__ Kd, _Float16* __restrict__ Vt,
    const unsigned short* __restrict__ xdet) {
  __shared__ __align__(16) char smem[32768];  // A slots @0,8192 | B @16384,24576
  _Float16* Tb = (_Float16*)smem;             // V epilogue reuse (17.4KB)

  const int f = detect_bf16_flag(xdet);
  const bf16_t* A = f ? (const bf16_t*)xdet : xb;

  const int tid = threadIdx.x;
  const int n0 = blockIdx.x * 128, m0 = blockIdx.y * 128;
  const int r = tid >> 2, c8 = (tid & 3) << 3;
  const bf16_t* Ag = A + (size_t)(m0 + r) * 768 + c8;
  const bf16_t* Bg = Bm + (size_t)(n0 + r) * 768 + c8;
  const int wid = tid >> 6, lane = tid & 63;
  const int wm = (wid >> 1) << 6, wn = (wid & 1) << 6;
  const int lr = lane & 15, lk = (lane >> 4) << 3, g4 = (lane >> 4) << 2;

  f32x4 acc[4][4];
  const f32x4 z = {0.f, 0.f, 0.f, 0.f};
#pragma unroll
  for (int i = 0; i < 4; i++)
#pragma unroll
    for (int j = 0; j < 4; j++) acc[i][j] = z;

  {  // stage k0=0 -> slot 0
    bf16_t* A0 = (bf16_t*)smem;
    bf16_t* B0 = (bf16_t*)(smem + 16384);
    glds16(Ag, A0 + wid * 512);
    glds16(Ag + (size_t)64 * 768, A0 + 2048 + wid * 512);
    glds16(Bg, B0 + wid * 512);
    glds16(Bg + (size_t)64 * 768, B0 + 2048 + wid * 512);
  }
  __syncthreads();

  for (int s = 0; s < 24; s++) {
    if (s < 23) {  // prefetch s+1 into other slot (overlaps compute below)
      const int k0 = (s + 1) * 32;
      bf16_t* An = (bf16_t*)(smem + ((s + 1) & 1) * 8192);
      bf16_t* Bn = (bf16_t*)(smem + 16384 + ((s + 1) & 1) * 8192);
      glds16(Ag + k0, An + wid * 512);
      glds16(Ag + (size_t)64 * 768 + k0, An + 2048 + wid * 512);
      glds16(Bg + k0, Bn + wid * 512);
      glds16(Bg + (size_t)64 * 768 + k0, Bn + 2048 + wid * 512);
    }
    const bf16_t* As = (const bf16_t*)(smem + (s & 1) * 8192);
    const bf16_t* Bs = (const bf16_t*)(smem + 16384 + (s & 1) * 8192);
    bf16x8 af[4], bf_[4];
#pragma unroll
    for (int t = 0; t < 4; t++) af[t]  = *(const bf16x8*)&As[(wm + t * 16 + lr) * 32 + lk];
#pragma unroll
    for (int t = 0; t < 4; t++) bf_[t] = *(const bf16x8*)&Bs[(wn + t * 16 + lr) * 32 + lk];
#pragma unroll
    for (int i = 0; i < 4; i++)
#pragma unroll
      for (int j = 0; j < 4; j++)
        acc[i][j] = __builtin_amdgcn_mfma_f32_16x16x32_bf16(af[i], bf_[j], acc[i][j], 0, 0, 0);
    __syncthreads();  // joins waves + drains this iter's DMA (issued pre-compute)
  }

  if (n0 < 1536) {  // Q or K: scatter (16-lane runs contiguous over d)
    bf16_t* dst = (n0 < 768) ? Qd : Kd;
    const int nb = (n0 < 768) ? n0 : n0 - 768;
    const int bb = m0 >> 11;
#pragma unroll
    for (int i = 0; i < 4; i++)
#pragma unroll
      for (int j = 0; j < 4; j++) {
        const int rc = nb + wn + j * 16 + lr;
        const int hh = rc >> 6, dd = rc & 63;
        const size_t base = (((size_t)bb * 12 + hh) * 2048) * 64 + dd;
#pragma unroll
        for (int reg = 0; reg < 4; reg++) {
          const int s = (m0 & 2047) + wm + i * 16 + g4 + reg;
          dst[base + (size_t)s * 64] = (bf16_t)acc[i][j][reg];
        }
      }
  } else {  // V: LDS transpose -> coalesced V^T f16 writes
    const int bb = m0 >> 11;
#pragma unroll
    for (int half = 0; half < 2; half++) {
      if ((wid & 1) == half) {
#pragma unroll
        for (int j = 0; j < 4; j++) {
          const int d_l = j * 16 + lr;
#pragma unroll
          for (int i = 0; i < 4; i++)
#pragma unroll
            for (int reg = 0; reg < 4; reg++)
              Tb[d_l * 136 + wm + i * 16 + g4 + reg] = (_Float16)acc[i][j][reg];
        }
      }
      __syncthreads();
      const int row = tid >> 2, cc = (tid & 3) * 32;
      const int vcol = (n0 - 1536) + half * 64 + row;
      const int hh = vcol >> 6;  // d == row
      _Float16* dstv = Vt + (((size_t)bb * 12 + hh) * 64 + row) * 2048 + (m0 & 2047) + cc;
#pragma unroll
      for (int u = 0; u < 4; u++)
        *(uint4*)(dstv + u * 8) = *(const uint4*)&Tb[row * 136 + cc + u * 8];
      __syncthreads();
    }
  }
}

// ----------------------------------------------------------- flash attention
// 768 blocks x 320 thr, 4 consumers + producer, double-buffer.
// K staged into PERMUTED slots: LDS slot s holds key pi(s),
// pi(32c+16h+4q+r) = 32c+8q+4h+r. QK output sv[ct][reg]@quad then has
// key = 32*(ct>>1) + 8*quad + 4*(ct&1) + reg, and the lane's own 16
// P-values pack natively into two f16x8 K=32 B-fragments (keys ct2*32+
// quad*8+j in natural order). V staged as [64d][64k] f16 tile, XOR-swizzled
// (byte ^= (d&7)<<4) -> conflict-free b128 A-fragments.
__global__ __launch_bounds__(320, 4) void k_flash(
    const bf16_t* __restrict__ Qd, const bf16_t* __restrict__ Kd,
    const _Float16* __restrict__ Vt, const void* __restrict__ mask,
    const int* __restrict__ mflags, const unsigned short* __restrict__ xdet,
    bf16_t* __restrict__ attn) {
  __shared__ __align__(16) char sm[32768];  // buf p at p*16384: K 8KB | V 8KB

  const int tid = threadIdx.x, wid = tid >> 6, lane = tid & 63;
  const int lr = lane & 15, quad = lane >> 4, lk = quad << 3, g4 = quad << 2;

  const int lin = blockIdx.x;
  const int gx = lin & 7, ww = lin >> 3;
  const int hb = gx * 3 + (ww >> 5);
  const int h = hb % 12, bb = hb / 12;
  const int qt = ww & 31;

  const size_t bh = (size_t)bb * 12 + h;
  const char* Kh = (const char*)(Kd + bh * 2048 * 64);
  const char* Vh = (const char*)(Vt + bh * 64 * 2048);

  if (wid == 4) {  // -------- producer
    const char* kS[8]; const char* vS[8];
    int kL[8], vL[8];
#pragma unroll
    for (int u = 0; u < 8; u++) {
      const int R = (u >> 1) * 16 + lr;          // global key row in tile
      const int cG = (u & 1) * 4 + quad;         // 16B d-chunk 0..7
      kS[u] = Kh + R * 128 + cG * 16;
      // permuted slot s = pi^-1(R): 32*(u>>2) + 16*((lr>>2)&1) +
      //                              8*((u>>1)&1) + 4*(lr>>3) + (lr&3)
      const int s = ((u >> 2) << 5) + (((lr >> 2) & 1) << 4) +
                    (((u >> 1) & 1) << 3) + ((lr >> 3) << 2) + (lr & 3);
      kL[u] = (s >> 4) * 2048 + (cG & 3) * 256 + (s & 15) * 16 + (cG >> 2) * 1024;
      // V: row d = lane, 8 x 16B key-chunks, XOR-swizzled within the 128B row
      vS[u] = Vh + (size_t)lane * 4096 + u * 16;
      vL[u] = 8192 + lane * 128 + ((u * 16) ^ ((lane & 7) << 4));
    }
    uint4 kv[8], vv[8];
#pragma unroll
    for (int u = 0; u < 8; u++) kv[u] = *(const uint4*)(kS[u]);
#pragma unroll
    for (int u = 0; u < 8; u++) vv[u] = *(const uint4*)(vS[u]);
#pragma unroll
    for (int u = 0; u < 8; u++) *(uint4*)(sm + kL[u]) = kv[u];
#pragma unroll
    for (int u = 0; u < 8; u++) *(uint4*)(sm + vL[u]) = vv[u];
    __syncthreads();
    for (int s = 0; s < 32; s++) {
      if (s < 31) {
        const int t = s + 1;
        char* buf = sm + (t & 1) * 16384;
#pragma unroll
        for (int u = 0; u < 8; u++) kv[u] = *(const uint4*)(kS[u] + (size_t)t * 8192);
#pragma unroll
        for (int u = 0; u < 8; u++) vv[u] = *(const uint4*)(vS[u] + (size_t)t * 128);
#pragma unroll
        for (int u = 0; u < 8; u++) *(uint4*)(buf + kL[u]) = kv[u];
#pragma unroll
        for (int u = 0; u < 8; u++) *(uint4*)(buf + vL[u]) = vv[u];
      }
      __syncthreads();
    }
    return;
  }

  // -------- consumers
  const bf16_t* Qh = Qd + bh * 2048 * 64;
  const int q0 = qt * 64 + wid * 16;
  const int mbf = detect_bf16_flag(xdet);
  const int* mfrow = mflags + (qt >> 1) * 16;
  int mbits = 0;
#pragma unroll
  for (int t = 0; t < 16; t++) mbits |= (mfrow[t] != 0) << t;

  const bf16x8 qf0 = *(const bf16x8*)&Qh[(size_t)(q0 + lr) * 64 + lk];
  const bf16x8 qf1 = *(const bf16x8*)&Qh[(size_t)(q0 + lr) * 64 + 32 + lk];

  f16x8 ones8;
#pragma unroll
  for (int j = 0; j < 8; j++) ones8[j] = (_Float16)1.f;

  // V read offsets (per-lane constant): row = dt*16+lr, slot XOR by (lr&7)
  const int vxo0 = (quad * 16) ^ ((lr & 7) << 4);
  const int vxo1 = (64 + quad * 16) ^ ((lr & 7) << 4);

  const f32x4 z = {0.f, 0.f, 0.f, 0.f};
  f32x4 ot[4];
#pragma unroll
  for (int dt = 0; dt < 4; dt++) ot[dt] = z;
  float mrow = -1e30f, lrow = 0.f;

  __syncthreads();

  for (int s = 0; s < 32; s++) {
    const char* Kc = sm + (s & 1) * 16384;
    const char* Vc = Kc + 8192;

    f32x4 sv[4];
#pragma unroll
    for (int ct = 0; ct < 4; ct++) sv[ct] = z;
    __builtin_amdgcn_s_setprio(1);
#pragma unroll
    for (int ct = 0; ct < 4; ct++) {
      bf16x8 kf0 = *(const bf16x8*)(Kc + ct * 2048 + lane * 16);
      bf16x8 kf1 = *(const bf16x8*)(Kc + ct * 2048 + 1024 + lane * 16);
      sv[ct] = __builtin_amdgcn_mfma_f32_16x16x32_bf16(kf0, qf0, sv[ct], 0, 0, 0);
      sv[ct] = __builtin_amdgcn_mfma_f32_16x16x32_bf16(kf1, qf1, sv[ct], 0, 0, 0);
    }
    __builtin_amdgcn_s_setprio(0);

    if ((mbits >> (s >> 1)) & 1) {
#pragma unroll
      for (int ct = 0; ct < 4; ct++)
#pragma unroll
        for (int reg = 0; reg < 4; reg++) {
          // actual key of sv[ct][reg] under the slot permutation
          const int kk = ((ct >> 1) << 5) + (quad << 3) + ((ct & 1) << 2) + reg;
          size_t mi = (size_t)(q0 + lr) * 2048 + s * 64 + kk;
          float mv = mbf ? bf2f(((const unsigned short*)mask)[mi])
                         : ((const float*)mask)[mi];
          sv[ct][reg] -= 8e9f * mv;
        }
    }

    float t = fmaxf(
        fmaxf(fmaxf(fmaxf(sv[0][0], sv[0][1]), fmaxf(sv[0][2], sv[0][3])),
              fmaxf(fmaxf(sv[1][0], sv[1][1]), fmaxf(sv[1][2], sv[1][3]))),
        fmaxf(fmaxf(fmaxf(sv[2][0], sv[2][1]), fmaxf(sv[2][2], sv[2][3])),
              fmaxf(fmaxf(sv[3][0], sv[3][1]), fmaxf(sv[3][2], sv[3][3]))));
    t = fmaxf(t, __shfl_xor(t, 16));
    t = fmaxf(t, __shfl_xor(t, 32));
    // T13 defer-max: only rescale when some row grew past mrow+THR.
    // Otherwise keep stale mrow; exp2 args bounded by THR*SC2 ~= 8 (P<=256).
    if (__ballot(t > mrow + DEFER_THR)) {
      const float mnew = fmaxf(mrow, t);
      const float alpha = fexp2((mrow - mnew) * SC2);
#pragma unroll
      for (int dt = 0; dt < 4; dt++)
#pragma unroll
        for (int reg = 0; reg < 4; reg++) ot[dt][reg] *= alpha;
      lrow *= alpha;
      mrow = mnew;
    }
    const float mS = mrow * SC2;

    // P -> two f16x8 K=32 B-fragments (lane-local pack, zero shuffles)
    f16x8 pb8[2];
#pragma unroll
    for (int c2 = 0; c2 < 2; c2++) {
      union { hf2 h[4]; f16x8 v; } u;
#pragma unroll
      for (int hh2 = 0; hh2 < 2; hh2++) {
        const int ct = c2 * 2 + hh2;
        float p0 = fexp2(fmaf(sv[ct][0], SC2, -mS));
        float p1 = fexp2(fmaf(sv[ct][1], SC2, -mS));
        float p2 = fexp2(fmaf(sv[ct][2], SC2, -mS));
        float p3 = fexp2(fmaf(sv[ct][3], SC2, -mS));
        u.h[hh2 * 2 + 0] = __builtin_amdgcn_cvt_pkrtz(p0, p1);
        u.h[hh2 * 2 + 1] = __builtin_amdgcn_cvt_pkrtz(p2, p3);
      }
      pb8[c2] = u.v;
    }

    f32x4 asum = z;
    __builtin_amdgcn_s_setprio(1);
#pragma unroll
    for (int c2 = 0; c2 < 2; c2++) {
      const int vxo = c2 ? vxo1 : vxo0;
      asum = __builtin_amdgcn_mfma_f32_16x16x32_f16(ones8, pb8[c2], asum, 0, 0, 0);
#pragma unroll
      for (int dt = 0; dt < 4; dt++) {
        f16x8 va = *(const f16x8*)(Vc + (dt * 16 + lr) * 128 + vxo);
        ot[dt] = __builtin_amdgcn_mfma_f32_16x16x32_f16(va, pb8[c2], ot[dt], 0, 0, 0);
      }
    }
    __builtin_amdgcn_s_setprio(0);
    lrow += asum[0];
    __syncthreads();
  }

  const float inv = 1.0f / lrow;
  bf16_t* arow = attn + ((size_t)bb * 2048 + q0 + lr) * 768 + h * 64 + g4;
#pragma unroll
  for (int dt = 0; dt < 4; dt++) {
    bf16x4 v;
#pragma unroll
    for (int reg = 0; reg < 4; reg++) v[reg] = (bf16_t)(ot[dt][reg] * inv);
    *(bf16x4*)(arow + dt * 16) = v;
  }
}

// -------------------------------------------------- output GEMM (attn @ Wo^T)
// 64x64 tiles -> 768 blocks (3/CU), BK=64 double-buffered with
// prefetch-before-compute (two 32-k sub-tiles per slot).
__global__ __launch_bounds__(256, 3) void k_gemm2(
    const bf16_t* __restrict__ A, const bf16_t* __restrict__ Bm,
    const void* __restrict__ bo, const unsigned short* __restrict__ xdet,
    float* __restrict__ outF, unsigned short* __restrict__ outH) {
  __shared__ __align__(16) char smem[32768];  // A slots @0,8192 | B @16384,24576

  const int tid = threadIdx.x, wid = tid >> 6, lane = tid & 63;
  const int n0 = blockIdx.x * 64, m0 = blockIdx.y * 64;
  const int wm = (wid >> 1) << 5, wn = (wid & 1) << 5;
  const int lr = lane & 15, lk = (lane >> 4) << 3, g4 = (lane >> 4) << 2;
  const bf16_t* Ag = A + (size_t)(m0 + (tid >> 2)) * 768 + ((tid & 3) << 3);
  const bf16_t* Bg = Bm + (size_t)(n0 + (tid >> 2)) * 768 + ((tid & 3) << 3);

  f32x4 acc[2][2];
  const f32x4 z = {0.f, 0.f, 0.f, 0.f};
#pragma unroll
  for (int i = 0; i < 2; i++)
#pragma unroll
    for (int j = 0; j < 2; j++) acc[i][j] = z;

  {  // stage k0=0 -> slot 0 (two 32-k halves per operand)
    bf16_t* A0 = (bf16_t*)smem;
    bf16_t* B0 = (bf16_t*)(smem + 16384);
    glds16(Ag, A0 + wid * 512);
    glds16(Ag + 32, A0 + 2048 + wid * 512);
    glds16(Bg, B0 + wid * 512);
    glds16(Bg + 32, B0 + 2048 + wid * 512);
  }
  __syncthreads();

  for (int s = 0; s < 12; s++) {
    if (s < 11) {  // prefetch s+1 into other slot
      const int k0 = (s + 1) * 64;
      bf16_t* An = (bf16_t*)(smem + ((s + 1) & 1) * 8192);
      bf16_t* Bn = (bf16_t*)(smem + 16384 + ((s + 1) & 1) * 8192);
      glds16(Ag + k0, An + wid * 512);
      glds16(Ag + k0 + 32, An + 2048 + wid * 512);
      glds16(Bg + k0, Bn + wid * 512);
      glds16(Bg + k0 + 32, Bn + 2048 + wid * 512);
    }
#pragma unroll
    for (int kc = 0; kc < 2; kc++) {
      const bf16_t* As = (const bf16_t*)(smem + (s & 1) * 8192) + kc * 2048;
      const bf16_t* Bs = (const bf16_t*)(smem + 16384 + (s & 1) * 8192) + kc * 2048;
      bf16x8 af[2], bf_[2];
#pragma unroll
      for (int i = 0; i < 2; i++) af[i]  = *(const bf16x8*)&As[(wm + i * 16 + lr) * 32 + lk];
#pragma unroll
      for (int j = 0; j < 2; j++) bf_[j] = *(const bf16x8*)&Bs[(wn + j * 16 + lr) * 32 + lk];
#pragma unroll
      for (int i = 0; i < 2; i++)
#pragma unroll
        for (int j = 0; j < 2; j++)
          acc[i][j] = __builtin_amdgcn_mfma_f32_16x16x32_bf16(af[i], bf_[j], acc[i][j], 0, 0, 0);
    }
    __syncthreads();
  }

  const int obf = detect_bf16_flag(xdet);
#pragma unroll
  for (int i = 0; i < 2; i++)
#pragma unroll
    for (int j = 0; j < 2; j++) {
      const int nn = n0 + wn + j * 16 + lr;
      const float bv = obf ? bf2f(((const unsigned short*)bo)[nn])
                           : ((const float*)bo)[nn];
#pragma unroll
      for (int reg = 0; reg < 4; reg++) {
        const int m = m0 + wm + i * 16 + g4 + reg;
        const float v = acc[i][j][reg] + bv;
        if (obf) outH[(size_t)m * 768 + nn] = __builtin_bit_cast(unsigned short, (bf16_t)v);
        else     outF[(size_t)m * 768 + nn] = v;
      }
    }
}

// -------------------------------------------------------------------- launch
extern "C" void kernel_launch(void* const* d_in, const int* in_sizes, int n_in,
                              void* d_out, int out_size, void* d_ws, size_t ws_size,
                              hipStream_t stream) {
  (void)in_sizes; (void)n_in; (void)out_size; (void)ws_size;
  const void* x    = d_in[0];
  const void* mask = d_in[1];
  const void* Wq   = d_in[2];
  const void* Wk   = d_in[3];
  const void* Wv   = d_in[4];
  const void* Wo   = d_in[5];
  const void* bo   = d_in[6];

  char* w = (char*)d_ws;
  size_t off = 0;
  auto take = [&](size_t b) -> void* {
    void* p = w + off;
    off = (off + b + 255) & ~(size_t)255;
    return p;
  };
  int*      mflags = (int*)take(256 * 4);
  bf16_t*   wqkvT  = (bf16_t*)take((size_t)2304 * 768 * 2);
  bf16_t*   woT    = (bf16_t*)take((size_t)768 * 768 * 2);
  bf16_t*   xb     = (bf16_t*)take((size_t)4096 * 768 * 2);
  bf16_t*   Qd     = (bf16_t*)take((size_t)3145728 * 2);
  bf16_t*   Kd     = (bf16_t*)take((size_t)3145728 * 2);
  _Float16* Vt     = (_Float16*)take((size_t)3145728 * 2);
  bf16_t*   attn   = xb;  // xb dead after QKV GEMM (flash output reuses it)

  k_prep<<<4096, 256, 0, stream>>>(x, mask, Wq, Wk, Wv, Wo, xb, wqkvT, woT, mflags);
  k_gemmQKV<<<dim3(18, 32), 256, 0, stream>>>(xb, wqkvT, Qd, Kd, Vt,
                                              (const unsigned short*)x);
  k_flash<<<768, 320, 0, stream>>>(Qd, Kd, Vt, mask, mflags,
                                   (const unsigned short*)x, attn);
  k_gemm2<<<dim3(12, 64), 256, 0, stream>>>(attn, woT, bo, (const unsigned short*)x,
                                            (float*)d_out, (unsigned short*)d_out);
}

// Round 3
// 172.162 us; speedup vs baseline: 1.0416x; 1.0342x over previous
//
#include <hip/hip_runtime.h>

// MultiHeadSelfAttention: B=2, S=2048, E=768, H=12, D=64
// R15: producer wave eliminated. The R14 LDS image (permuted K slots,
//      XOR-swizzled V rows) is now pre-baked into Kd/Vt GLOBAL layouts by
//      k_gemmQKV's epilogue, making each 64-key tile a contiguous 8KB block.
//      Flash stages K/V via global_load_lds (4 glds16/thread/iter),
//      prefetch-before-compute, 256 thr / 4 compute waves, 1 barrier/iter.
//      Consumer math identical to R14 (full-rate K=32 f16 PV, T5 setprio,
//      T13 defer-max). prep/gemm2 unchanged.

typedef __bf16 bf16_t;
typedef bf16_t bf16x8 __attribute__((ext_vector_type(8)));
typedef bf16_t bf16x4 __attribute__((ext_vector_type(4)));
typedef float f32x4 __attribute__((ext_vector_type(4)));
typedef _Float16 f16x4 __attribute__((ext_vector_type(4)));
typedef _Float16 f16x8 __attribute__((ext_vector_type(8)));
typedef __fp16 hf2 __attribute__((ext_vector_type(2)));

#define SC2 0.1803368801111137f  // 0.125 * log2(e): qk-scale folded into exp2
#define DEFER_THR 44.0f          // ~8/SC2: defer-max rescale threshold (T13)

__device__ __forceinline__ float bf2f(unsigned short u) {
  union { unsigned int i; float f; } x;
  x.i = ((unsigned int)u) << 16;
  return x.f;
}

__device__ __forceinline__ float fexp2(float x) {
  return __builtin_amdgcn_exp2f(x);  // raw v_exp_f32; args <= 8 here, FTZ exact
}

__device__ __forceinline__ void glds16(const bf16_t* g, bf16_t* l) {
  __builtin_amdgcn_global_load_lds(
      (const __attribute__((address_space(1))) void*)g,
      (__attribute__((address_space(3))) void*)l, 16, 0, 0);
}

// dtype probe: wave examines first 1024 u16 words of x. fp32 data => low
// halves carry random mantissa bits => wild bf16 exponents.
__device__ __forceinline__ int detect_bf16_flag(const unsigned short* x) {
  const int lane = threadIdx.x & 63;
  const uint4* p = (const uint4*)x;
  uint4 a = p[lane * 2];
  uint4 b = p[lane * 2 + 1];
  unsigned int w[8] = {a.x, a.y, a.z, a.w, b.x, b.y, b.z, b.w};
  unsigned int big = 0;
#pragma unroll
  for (int i = 0; i < 8; i++) {
    unsigned int e0 = (w[i] >> 7) & 0xFF, e1 = (w[i] >> 23) & 0xFF;
    big |= (e0 > 0x88u) | (e1 > 0x88u);
  }
  unsigned long long bal = __ballot(big != 0u);
  return bal == 0ULL ? 1 : 0;  // 1 => bf16 inputs
}

// ---------------------------------------------------------------- fused prep
__global__ void k_prep(const void* __restrict__ x, const void* __restrict__ mask,
                       const void* __restrict__ Wq, const void* __restrict__ Wk,
                       const void* __restrict__ Wv, const void* __restrict__ Wo,
                       bf16_t* __restrict__ xb, bf16_t* __restrict__ wqkvT,
                       bf16_t* __restrict__ woT, int* __restrict__ mflags) {
  __shared__ float ts[32][33];
  __shared__ int snz;
  const int blk = blockIdx.x;
  const int f = detect_bf16_flag((const unsigned short*)x);

  if (blk < 1536) {  // ---- ingest x (fp32 only; bf16 path reads x directly)
    if (f) return;
    int i = blk * 256 + threadIdx.x;
    const float* xf = (const float*)x + (size_t)i * 8;
    bf16x8 v;
#pragma unroll
    for (int j = 0; j < 8; j++) v[j] = (bf16_t)xf[j];
    *(bf16x8*)(xb + (size_t)i * 8) = v;
  } else if (blk < 3840) {  // ---- W transpose (4 matrices x 24x24 tiles)
    const int t = blk - 1536;
    const int z = t / 576, r = t % 576, kt = r / 24, nt = r % 24;
    const void* wsrc = (z == 0) ? Wq : (z == 1) ? Wk : (z == 2) ? Wv : Wo;
    bf16_t* dst = (z < 3) ? (wqkvT + (size_t)z * 768 * 768) : woT;
    const int c = threadIdx.x & 31, r0 = threadIdx.x >> 5;
#pragma unroll
    for (int i = 0; i < 4; i++) {
      int kr = kt * 32 + r0 + i * 8;
      float v;
      if (f) v = bf2f(((const unsigned short*)wsrc)[(size_t)kr * 768 + nt * 32 + c]);
      else   v = ((const float*)wsrc)[(size_t)kr * 768 + nt * 32 + c];
      ts[r0 + i * 8][c] = v;
    }
    __syncthreads();
#pragma unroll
    for (int i = 0; i < 4; i++) {
      int nr = nt * 32 + r0 + i * 8;
      dst[(size_t)nr * 768 + kt * 32 + c] = (bf16_t)ts[c][r0 + i * 8];
    }
  } else {  // ---- mask nonzero flag per 128x128 tile, uint4 loads
    const int t = blk - 3840;
    const int qt = t >> 4, ktm = t & 15;
    if (threadIdx.x == 0) snz = 0;
    __syncthreads();
    unsigned int nz = 0;
    if (f) {
#pragma unroll
      for (int i = 0; i < 8; i++) {
        int uidx = i * 256 + threadIdx.x;
        int row = uidx >> 4, col = uidx & 15;
        const uint4* p = (const uint4*)((const char*)mask +
            ((size_t)(qt * 128 + row) * 2048 + ktm * 128) * 2 + col * 16);
        uint4 v = *p;
        nz |= ((v.x | v.y | v.z | v.w) & 0x7fff7fffu);
      }
    } else {
#pragma unroll
      for (int i = 0; i < 16; i++) {
        int uidx = i * 256 + threadIdx.x;
        int row = uidx >> 5, col = uidx & 31;
        const uint4* p = (const uint4*)((const char*)mask +
            ((size_t)(qt * 128 + row) * 2048 + ktm * 128) * 4 + col * 16);
        uint4 v = *p;
        nz |= ((v.x | v.y | v.z | v.w) & 0x7fffffffu);
      }
    }
    if (nz) snz = 1;
    __syncthreads();
    if (threadIdx.x == 0) mflags[qt * 16 + ktm] = snz;
  }
}

// ------------------------------------------------------------------ QKV GEMM
// C[4096 x 2304] = A * wqkvT^T, 128x128 tile, BK=32 double-buffered with
// prefetch-before-compute. Epilogues now emit flash-ready tiled layouts:
//   Kd: per (b,h,64-key group) 8KB block = R14's producer LDS image
//       (slot sigma(w) permutation, [sg][dhalf][dquad][slo][8d] order)
//   Vt: per (b,h,64-key tile) 8KB block, [64d][128B row ^ ((d&7)<<4)]
__global__ __launch_bounds__(256, 3) void k_gemmQKV(
    const bf16_t* __restrict__ xb, const bf16_t* __restrict__ Bm,
    bf16_t* __restrict__ Qd, char* __restrict__ Kd, char* __restrict__ Vt,
    const unsigned short* __restrict__ xdet) {
  __shared__ __align__(16) char smem[32768];  // A slots @0,8192 | B @16384,24576
  _Float16* Tb = (_Float16*)smem;             // V epilogue reuse (17.4KB)

  const int f = detect_bf16_flag(xdet);
  const bf16_t* A = f ? (const bf16_t*)xdet : xb;

  const int tid = threadIdx.x;
  const int n0 = blockIdx.x * 128, m0 = blockIdx.y * 128;
  const int r = tid >> 2, c8 = (tid & 3) << 3;
  const bf16_t* Ag = A + (size_t)(m0 + r) * 768 + c8;
  const bf16_t* Bg = Bm + (size_t)(n0 + r) * 768 + c8;
  const int wid = tid >> 6, lane = tid & 63;
  const int wm = (wid >> 1) << 6, wn = (wid & 1) << 6;
  const int lr = lane & 15, quad = lane >> 4, lk = quad << 3, g4 = quad << 2;

  f32x4 acc[4][4];
  const f32x4 z = {0.f, 0.f, 0.f, 0.f};
#pragma unroll
  for (int i = 0; i < 4; i++)
#pragma unroll
    for (int j = 0; j < 4; j++) acc[i][j] = z;

  {  // stage k0=0 -> slot 0
    bf16_t* A0 = (bf16_t*)smem;
    bf16_t* B0 = (bf16_t*)(smem + 16384);
    glds16(Ag, A0 + wid * 512);
    glds16(Ag + (size_t)64 * 768, A0 + 2048 + wid * 512);
    glds16(Bg, B0 + wid * 512);
    glds16(Bg + (size_t)64 * 768, B0 + 2048 + wid * 512);
  }
  __syncthreads();

  for (int s = 0; s < 24; s++) {
    if (s < 23) {  // prefetch s+1 into other slot (overlaps compute below)
      const int k0 = (s + 1) * 32;
      bf16_t* An = (bf16_t*)(smem + ((s + 1) & 1) * 8192);
      bf16_t* Bn = (bf16_t*)(smem + 16384 + ((s + 1) & 1) * 8192);
      glds16(Ag + k0, An + wid * 512);
      glds16(Ag + (size_t)64 * 768 + k0, An + 2048 + wid * 512);
      glds16(Bg + k0, Bn + wid * 512);
      glds16(Bg + (size_t)64 * 768 + k0, Bn + 2048 + wid * 512);
    }
    const bf16_t* As = (const bf16_t*)(smem + (s & 1) * 8192);
    const bf16_t* Bs = (const bf16_t*)(smem + 16384 + (s & 1) * 8192);
    bf16x8 af[4], bf_[4];
#pragma unroll
    for (int t = 0; t < 4; t++) af[t]  = *(const bf16x8*)&As[(wm + t * 16 + lr) * 32 + lk];
#pragma unroll
    for (int t = 0; t < 4; t++) bf_[t] = *(const bf16x8*)&Bs[(wn + t * 16 + lr) * 32 + lk];
#pragma unroll
    for (int i = 0; i < 4; i++)
#pragma unroll
      for (int j = 0; j < 4; j++)
        acc[i][j] = __builtin_amdgcn_mfma_f32_16x16x32_bf16(af[i], bf_[j], acc[i][j], 0, 0, 0);
    __syncthreads();  // joins waves + drains this iter's DMA (issued pre-compute)
  }

  if (n0 < 768) {  // Q: natural [seq][d] scatter
    const int bb = m0 >> 11;
#pragma unroll
    for (int i = 0; i < 4; i++)
#pragma unroll
      for (int j = 0; j < 4; j++) {
        const int rc = n0 + wn + j * 16 + lr;
        const int hh = rc >> 6, dd = rc & 63;
        const size_t base = (((size_t)bb * 12 + hh) * 2048) * 64 + dd;
#pragma unroll
        for (int reg = 0; reg < 4; reg++) {
          const int s = (m0 & 2047) + wm + i * 16 + g4 + reg;
          Qd[base + (size_t)s * 64] = (bf16_t)acc[i][j][reg];
        }
      }
  } else if (n0 < 1536) {  // K: permuted-slot tiled layout (flash LDS image)
    const int nb = n0 - 768;
    const int bb = m0 >> 11;
    const int g = ((m0 & 2047) + wm) >> 6;  // 64-key group
#pragma unroll
    for (int i = 0; i < 4; i++) {
#pragma unroll
      for (int j = 0; j < 4; j++) {
        const int rc = nb + wn + j * 16 + lr;
        const int hh = rc >> 6, dd = rc & 63;
        const size_t tbase = ((size_t)((bb * 12 + hh) * 32 + g)) << 13;
        const int doff = ((dd >> 5) << 10) + (((dd >> 3) & 3) << 8) + ((dd & 7) << 1);
#pragma unroll
        for (int reg = 0; reg < 4; reg++) {
          // slot sigma(w), w = 16i + 4*quad + reg (within-64 key index)
          const int sig = ((i >> 1) << 5) + ((quad & 1) << 4) +
                          (((((i & 1) << 1) | (quad >> 1))) << 2) + reg;
          *(bf16_t*)(Kd + tbase + ((sig >> 4) << 11) + ((sig & 15) << 4) + doff) =
              (bf16_t)acc[i][j][reg];
        }
      }
    }
  } else {  // V: LDS transpose -> tiled swizzled [64d][128B^swz] blocks
    const int bb = m0 >> 11;
#pragma unroll
    for (int half = 0; half < 2; half++) {
      if ((wid & 1) == half) {
#pragma unroll
        for (int j = 0; j < 4; j++) {
          const int d_l = j * 16 + lr;
#pragma unroll
          for (int i = 0; i < 4; i++)
#pragma unroll
            for (int reg = 0; reg < 4; reg++)
              Tb[d_l * 136 + wm + i * 16 + g4 + reg] = (_Float16)acc[i][j][reg];
        }
      }
      __syncthreads();
      const int row = tid >> 2, cc = (tid & 3) * 32;  // row = d (0..63)
      const int vcol = (n0 - 1536) + half * 64 + row;
      const int hh = vcol >> 6;
      const int g = ((m0 & 2047) + cc) >> 6;          // 64-key tile
      const int koff2 = (cc & 63) * 2;                // 0 or 64 bytes
      char* vb = Vt + (((size_t)((bb * 12 + hh) * 32 + g)) << 13) + (row << 7);
#pragma unroll
      for (int u = 0; u < 4; u++)
        *(uint4*)(vb + ((koff2 + u * 16) ^ ((row & 7) << 4))) =
            *(const uint4*)&Tb[row * 136 + cc + u * 8];
      __syncthreads();
    }
  }
}

// ----------------------------------------------------------- flash attention
// 768 blocks x 256 thr, 4 compute waves, no producer. K/V tiles are
// contiguous 8KB blocks in global (pre-permuted/swizzled by gemmQKV), staged
// via global_load_lds double-buffered, prefetch-before-compute, 1 barrier/iter.
// Consumer math = R14: full-rate K=32 f16 PV, lane-local P pack, T5, T13.
__global__ __launch_bounds__(256, 4) void k_flash(
    const bf16_t* __restrict__ Qd, const char* __restrict__ Kd,
    const char* __restrict__ Vt, const void* __restrict__ mask,
    const int* __restrict__ mflags, const unsigned short* __restrict__ xdet,
    bf16_t* __restrict__ attn) {
  __shared__ __align__(16) char sm[32768];  // buf p at p*16384: K 8KB | V 8KB

  const int tid = threadIdx.x, wid = tid >> 6, lane = tid & 63;
  const int lr = lane & 15, quad = lane >> 4, lk = quad << 3, g4 = quad << 2;

  const int lin = blockIdx.x;
  const int gx = lin & 7, ww = lin >> 3;
  const int hb = gx * 3 + (ww >> 5);
  const int h = hb % 12, bb = hb / 12;
  const int qt = ww & 31;

  const size_t bh = (size_t)bb * 12 + h;
  const char* Kg = Kd + (bh << 18);  // 32 tiles x 8KB = 256KB per (b,h)
  const char* Vg = Vt + (bh << 18);

  // DMA staging: each wave covers 2KB of K and 2KB of V per tile.
  const char* kgl = Kg + wid * 2048 + lane * 16;
  const char* vgl = Vg + wid * 2048 + lane * 16;

#define STAGE(t, buf)                                                      \
  {                                                                        \
    const size_t o_ = (size_t)(t) * 8192;                                  \
    glds16((const bf16_t*)(kgl + o_),        (bf16_t*)((buf) + wid * 2048));        \
    glds16((const bf16_t*)(kgl + o_ + 1024), (bf16_t*)((buf) + wid * 2048 + 1024)); \
    glds16((const bf16_t*)(vgl + o_),        (bf16_t*)((buf) + 8192 + wid * 2048)); \
    glds16((const bf16_t*)(vgl + o_ + 1024), (bf16_t*)((buf) + 8192 + wid * 2048 + 1024)); \
  }

  STAGE(0, sm);

  const bf16_t* Qh = Qd + bh * 2048 * 64;
  const int q0 = qt * 64 + wid * 16;
  const int mbf = detect_bf16_flag(xdet);
  const int* mfrow = mflags + (qt >> 1) * 16;
  int mbits = 0;
#pragma unroll
  for (int t = 0; t < 16; t++) mbits |= (mfrow[t] != 0) << t;

  const bf16x8 qf0 = *(const bf16x8*)&Qh[(size_t)(q0 + lr) * 64 + lk];
  const bf16x8 qf1 = *(const bf16x8*)&Qh[(size_t)(q0 + lr) * 64 + 32 + lk];

  f16x8 ones8;
#pragma unroll
  for (int j = 0; j < 8; j++) ones8[j] = (_Float16)1.f;

  // V read offsets (per-lane constant): row = dt*16+lr, chunk XOR by (lr&7)
  const int vxo0 = (quad * 16) ^ ((lr & 7) << 4);
  const int vxo1 = (64 + quad * 16) ^ ((lr & 7) << 4);

  const f32x4 z = {0.f, 0.f, 0.f, 0.f};
  f32x4 ot[4];
#pragma unroll
  for (int dt = 0; dt < 4; dt++) ot[dt] = z;
  float mrow = -1e30f, lrow = 0.f;

  __syncthreads();  // drains STAGE(0), joins waves

  for (int s = 0; s < 32; s++) {
    if (s < 31) STAGE(s + 1, sm + (((s + 1) & 1) << 14));

    const char* Kc = sm + ((s & 1) << 14);
    const char* Vc = Kc + 8192;

    f32x4 sv[4];
#pragma unroll
    for (int ct = 0; ct < 4; ct++) sv[ct] = z;
    __builtin_amdgcn_s_setprio(1);
#pragma unroll
    for (int ct = 0; ct < 4; ct++) {
      bf16x8 kf0 = *(const bf16x8*)(Kc + ct * 2048 + lane * 16);
      bf16x8 kf1 = *(const bf16x8*)(Kc + ct * 2048 + 1024 + lane * 16);
      sv[ct] = __builtin_amdgcn_mfma_f32_16x16x32_bf16(kf0, qf0, sv[ct], 0, 0, 0);
      sv[ct] = __builtin_amdgcn_mfma_f32_16x16x32_bf16(kf1, qf1, sv[ct], 0, 0, 0);
    }
    __builtin_amdgcn_s_setprio(0);

    if ((mbits >> (s >> 1)) & 1) {
#pragma unroll
      for (int ct = 0; ct < 4; ct++)
#pragma unroll
        for (int reg = 0; reg < 4; reg++) {
          // actual key of sv[ct][reg] under the slot permutation
          const int kk = ((ct >> 1) << 5) + (quad << 3) + ((ct & 1) << 2) + reg;
          size_t mi = (size_t)(q0 + lr) * 2048 + s * 64 + kk;
          float mv = mbf ? bf2f(((const unsigned short*)mask)[mi])
                         : ((const float*)mask)[mi];
          sv[ct][reg] -= 8e9f * mv;
        }
    }

    float t = fmaxf(
        fmaxf(fmaxf(fmaxf(sv[0][0], sv[0][1]), fmaxf(sv[0][2], sv[0][3])),
              fmaxf(fmaxf(sv[1][0], sv[1][1]), fmaxf(sv[1][2], sv[1][3]))),
        fmaxf(fmaxf(fmaxf(sv[2][0], sv[2][1]), fmaxf(sv[2][2], sv[2][3])),
              fmaxf(fmaxf(sv[3][0], sv[3][1]), fmaxf(sv[3][2], sv[3][3]))));
    t = fmaxf(t, __shfl_xor(t, 16));
    t = fmaxf(t, __shfl_xor(t, 32));
    // T13 defer-max: only rescale when some row grew past mrow+THR.
    if (__ballot(t > mrow + DEFER_THR)) {
      const float mnew = fmaxf(mrow, t);
      const float alpha = fexp2((mrow - mnew) * SC2);
#pragma unroll
      for (int dt = 0; dt < 4; dt++)
#pragma unroll
        for (int reg = 0; reg < 4; reg++) ot[dt][reg] *= alpha;
      lrow *= alpha;
      mrow = mnew;
    }
    const float mS = mrow * SC2;

    // P -> two f16x8 K=32 B-fragments (lane-local pack, zero shuffles)
    f16x8 pb8[2];
#pragma unroll
    for (int c2 = 0; c2 < 2; c2++) {
      union { hf2 h[4]; f16x8 v; } u;
#pragma unroll
      for (int hh2 = 0; hh2 < 2; hh2++) {
        const int ct = c2 * 2 + hh2;
        float p0 = fexp2(fmaf(sv[ct][0], SC2, -mS));
        float p1 = fexp2(fmaf(sv[ct][1], SC2, -mS));
        float p2 = fexp2(fmaf(sv[ct][2], SC2, -mS));
        float p3 = fexp2(fmaf(sv[ct][3], SC2, -mS));
        u.h[hh2 * 2 + 0] = __builtin_amdgcn_cvt_pkrtz(p0, p1);
        u.h[hh2 * 2 + 1] = __builtin_amdgcn_cvt_pkrtz(p2, p3);
      }
      pb8[c2] = u.v;
    }

    f32x4 asum = z;
    __builtin_amdgcn_s_setprio(1);
#pragma unroll
    for (int c2 = 0; c2 < 2; c2++) {
      const int vxo = c2 ? vxo1 : vxo0;
      asum = __builtin_amdgcn_mfma_f32_16x16x32_f16(ones8, pb8[c2], asum, 0, 0, 0);
#pragma unroll
      for (int dt = 0; dt < 4; dt++) {
        f16x8 va = *(const f16x8*)(Vc + (dt * 16 + lr) * 128 + vxo);
        ot[dt] = __builtin_amdgcn_mfma_f32_16x16x32_f16(va, pb8[c2], ot[dt], 0, 0, 0);
      }
    }
    __builtin_amdgcn_s_setprio(0);
    lrow += asum[0];
    __syncthreads();  // joins waves + drains next tile's DMA
  }
#undef STAGE

  const float inv = 1.0f / lrow;
  bf16_t* arow = attn + ((size_t)bb * 2048 + q0 + lr) * 768 + h * 64 + g4;
#pragma unroll
  for (int dt = 0; dt < 4; dt++) {
    bf16x4 v;
#pragma unroll
    for (int reg = 0; reg < 4; reg++) v[reg] = (bf16_t)(ot[dt][reg] * inv);
    *(bf16x4*)(arow + dt * 16) = v;
  }
}

// -------------------------------------------------- output GEMM (attn @ Wo^T)
// 64x64 tiles -> 768 blocks (3/CU), BK=64 double-buffered with
// prefetch-before-compute (two 32-k sub-tiles per slot).
__global__ __launch_bounds__(256, 3) void k_gemm2(
    const bf16_t* __restrict__ A, const bf16_t* __restrict__ Bm,
    const void* __restrict__ bo, const unsigned short* __restrict__ xdet,
    float* __restrict__ outF, unsigned short* __restrict__ outH) {
  __shared__ __align__(16) char smem[32768];  // A slots @0,8192 | B @16384,24576

  const int tid = threadIdx.x, wid = tid >> 6, lane = tid & 63;
  const int n0 = blockIdx.x * 64, m0 = blockIdx.y * 64;
  const int wm = (wid >> 1) << 5, wn = (wid & 1) << 5;
  const int lr = lane & 15, lk = (lane >> 4) << 3, g4 = (lane >> 4) << 2;
  const bf16_t* Ag = A + (size_t)(m0 + (tid >> 2)) * 768 + ((tid & 3) << 3);
  const bf16_t* Bg = Bm + (size_t)(n0 + (tid >> 2)) * 768 + ((tid & 3) << 3);

  f32x4 acc[2][2];
  const f32x4 z = {0.f, 0.f, 0.f, 0.f};
#pragma unroll
  for (int i = 0; i < 2; i++)
#pragma unroll
    for (int j = 0; j < 2; j++) acc[i][j] = z;

  {  // stage k0=0 -> slot 0 (two 32-k halves per operand)
    bf16_t* A0 = (bf16_t*)smem;
    bf16_t* B0 = (bf16_t*)(smem + 16384);
    glds16(Ag, A0 + wid * 512);
    glds16(Ag + 32, A0 + 2048 + wid * 512);
    glds16(Bg, B0 + wid * 512);
    glds16(Bg + 32, B0 + 2048 + wid * 512);
  }
  __syncthreads();

  for (int s = 0; s < 12; s++) {
    if (s < 11) {  // prefetch s+1 into other slot
      const int k0 = (s + 1) * 64;
      bf16_t* An = (bf16_t*)(smem + ((s + 1) & 1) * 8192);
      bf16_t* Bn = (bf16_t*)(smem + 16384 + ((s + 1) & 1) * 8192);
      glds16(Ag + k0, An + wid * 512);
      glds16(Ag + k0 + 32, An + 2048 + wid * 512);
      glds16(Bg + k0, Bn + wid * 512);
      glds16(Bg + k0 + 32, Bn + 2048 + wid * 512);
    }
#pragma unroll
    for (int kc = 0; kc < 2; kc++) {
      const bf16_t* As = (const bf16_t*)(smem + (s & 1) * 8192) + kc * 2048;
      const bf16_t* Bs = (const bf16_t*)(smem + 16384 + (s & 1) * 8192) + kc * 2048;
      bf16x8 af[2], bf_[2];
#pragma unroll
      for (int i = 0; i < 2; i++) af[i]  = *(const bf16x8*)&As[(wm + i * 16 + lr) * 32 + lk];
#pragma unroll
      for (int j = 0; j < 2; j++) bf_[j] = *(const bf16x8*)&Bs[(wn + j * 16 + lr) * 32 + lk];
#pragma unroll
      for (int i = 0; i < 2; i++)
#pragma unroll
        for (int j = 0; j < 2; j++)
          acc[i][j] = __builtin_amdgcn_mfma_f32_16x16x32_bf16(af[i], bf_[j], acc[i][j], 0, 0, 0);
    }
    __syncthreads();
  }

  const int obf = detect_bf16_flag(xdet);
#pragma unroll
  for (int i = 0; i < 2; i++)
#pragma unroll
    for (int j = 0; j < 2; j++) {
      const int nn = n0 + wn + j * 16 + lr;
      const float bv = obf ? bf2f(((const unsigned short*)bo)[nn])
                           : ((const float*)bo)[nn];
#pragma unroll
      for (int reg = 0; reg < 4; reg++) {
        const int m = m0 + wm + i * 16 + g4 + reg;
        const float v = acc[i][j][reg] + bv;
        if (obf) outH[(size_t)m * 768 + nn] = __builtin_bit_cast(unsigned short, (bf16_t)v);
        else     outF[(size_t)m * 768 + nn] = v;
      }
    }
}

// -------------------------------------------------------------------- launch
extern "C" void kernel_launch(void* const* d_in, const int* in_sizes, int n_in,
                              void* d_out, int out_size, void* d_ws, size_t ws_size,
                              hipStream_t stream) {
  (void)in_sizes; (void)n_in; (void)out_size; (void)ws_size;
  const void* x    = d_in[0];
  const void* mask = d_in[1];
  const void* Wq   = d_in[2];
  const void* Wk   = d_in[3];
  const void* Wv   = d_in[4];
  const void* Wo   = d_in[5];
  const void* bo   = d_in[6];

  char* w = (char*)d_ws;
  size_t off = 0;
  auto take = [&](size_t b) -> void* {
    void* p = w + off;
    off = (off + b + 255) & ~(size_t)255;
    return p;
  };
  int*      mflags = (int*)take(256 * 4);
  bf16_t*   wqkvT  = (bf16_t*)take((size_t)2304 * 768 * 2);
  bf16_t*   woT    = (bf16_t*)take((size_t)768 * 768 * 2);
  bf16_t*   xb     = (bf16_t*)take((size_t)4096 * 768 * 2);
  bf16_t*   Qd     = (bf16_t*)take((size_t)3145728 * 2);
  char*     Kd     = (char*)take((size_t)3145728 * 2);
  char*     Vt     = (char*)take((size_t)3145728 * 2);
  bf16_t*   attn   = xb;  // xb dead after QKV GEMM (flash output reuses it)

  k_prep<<<4096, 256, 0, stream>>>(x, mask, Wq, Wk, Wv, Wo, xb, wqkvT, woT, mflags);
  k_gemmQKV<<<dim3(18, 32), 256, 0, stream>>>(xb, wqkvT, Qd, Kd, Vt,
                                              (const unsigned short*)x);
  k_flash<<<768, 256, 0, stream>>>(Qd, Kd, Vt, mask, mflags,
                                   (const unsigned short*)x, attn);
  k_gemm2<<<dim3(12, 64), 256, 0, stream>>>(attn, woT, bo, (const unsigned short*)x,
                                            (float*)d_out, (unsigned short*)d_out);
}